// Round 5
// baseline (21.568 us; speedup 1.0000x reference)
//
#include <hip/hip_runtime.h>
#include <math.h>

// JPEG layer: RGB->YCbCr, clip/shift, 2x2 chroma pool, 8x8 DCT, quantize, round.
// One 256-thread workgroup per 32x32 pixel tile.
//   per tile: 16 Y blocks (8x8), 4 Cb blocks, 4 Cr blocks. Grid = 16 images * 256 tiles.

static __device__ __forceinline__ float clip01(float v) {
    return fminf(fmaxf(v, 0.0f), 1.0f);
}

__global__ __launch_bounds__(256)
void jpeg_kernel(const float* __restrict__ rgb, const float* __restrict__ quant,
                 float* __restrict__ out)
{
    // single shared block with integer offsets -> guaranteed ds_read/ds_write addressing
    __shared__ __align__(16) float smem[4384];
    constexpr int YT  = 0;     // y   [32][36]
    constexpr int CBF = 1152;  // cb  clipped, PRE-subtract [32][36]
    constexpr int CRF = 2304;  // cr  clipped, PRE-subtract [32][36]
    constexpr int CB8 = 3456;  // pooled cb [16][18]
    constexpr int CR8 = 3744;  // pooled cr [16][18]
    constexpr int DM  = 4032;  // DCT matrix [8][8]
    constexpr int TMP = 4096;  // per-wave tmp [4][8][9]

    const int t = threadIdx.x;

    // DCT matrix in double (matches python math.cos path; sqrt(2/8) == 0.5 exactly)
    if (t < 64) {
        const int i = t >> 3, j = t & 7;
        double v;
        if (i == 0) v = 0.35355339059327373;           // 1/sqrt(8)
        else        v = 0.5 * cos(3.141592653589793 * (double)(2 * j + 1) * (double)i / 16.0);
        smem[DM + t] = (float)v;
    }

    const int wg   = blockIdx.x;
    const int b    = wg >> 8;         // image index (256 tiles per image)
    const int tile = wg & 255;
    const int th   = tile >> 4;       // tile row 0..15
    const int tw   = tile & 15;       // tile col 0..15

    // ---- color transform: 4 consecutive pixels per thread (float4 loads) ----
    {
        const int row = t >> 3;            // 0..31
        const int c4  = (t & 7) << 2;      // 0,4,...,28
        const float* p = rgb + ((size_t)b * 3) * 262144 + (size_t)(th * 32 + row) * 512 + (tw * 32 + c4);
        const float4 R  = *(const float4*)p;
        const float4 G  = *(const float4*)(p + 262144);
        const float4 Bv = *(const float4*)(p + 524288);
        const float OFF = (float)(128.0 / 255.0);
        const float rr[4] = {R.x, R.y, R.z, R.w};
        const float gg[4] = {G.x, G.y, G.z, G.w};
        const float bb[4] = {Bv.x, Bv.y, Bv.z, Bv.w};
        float yv[4], cbv[4], crv[4];
        #pragma unroll
        for (int k = 0; k < 4; ++k) {
            const float r_ = rr[k], g_ = gg[k], b_ = bb[k];
            const float y  = (float)(0.299) * r_ + (float)(0.587) * g_ + (float)(0.114) * b_;
            const float cb = (float)(-0.168735892) * r_ + (float)(-0.331264108) * g_ + 0.5f * b_;
            const float cr = 0.5f * r_ + (float)(-0.418687589) * g_ + (float)(-0.081312411) * b_;
            yv[k]  = clip01(y) - OFF;
            cbv[k] = clip01(cb + OFF);     // clipped, pre-subtract (subtract after pool)
            crv[k] = clip01(cr + OFF);
        }
        *(float4*)&smem[YT  + row * 36 + c4] = make_float4(yv[0], yv[1], yv[2], yv[3]);
        *(float4*)&smem[CBF + row * 36 + c4] = make_float4(cbv[0], cbv[1], cbv[2], cbv[3]);
        *(float4*)&smem[CRF + row * 36 + c4] = make_float4(crv[0], crv[1], crv[2], crv[3]);
    }
    __syncthreads();

    // ---- 2x2 chroma pooling: one output element per thread ----
    // HYPOTHESIS TEST (subtract OFF AFTER pooling — constant-add hoisted out of
    // the reduce). Cb tests the row-major chain; Cr tests balanced row-pairs.
    // All four sub-BEFORE orderings produced absmax-1.0 flips.
    {
        const float OFF = (float)(128.0 / 255.0);
        const int pr = t >> 4, pc = t & 15;
        const int o00 = (2 * pr) * 36 + 2 * pc;
        const int o10 = o00 + 36;
        // Cb: ((w00+w01)+w10)+w11, *0.25, then -OFF
        float sb = smem[CBF + o00];
        sb = sb + smem[CBF + o00 + 1];
        sb = sb + smem[CBF + o10];
        sb = sb + smem[CBF + o10 + 1];
        smem[CB8 + pr * 18 + pc] = sb * 0.25f - OFF;
        // Cr: (w00+w01)+(w10+w11), *0.25, then -OFF
        const float cr_r0 = smem[CRF + o00] + smem[CRF + o00 + 1];
        const float cr_r1 = smem[CRF + o10] + smem[CRF + o10 + 1];
        smem[CR8 + pr * 18 + pc] = (cr_r0 + cr_r1) * 0.25f - OFF;
    }
    __syncthreads();

    // ---- DCT + quantize: one wave (64 threads) per 8x8 block, 6 rounds of 4 blocks ----
    const int g = t >> 6;            // wave id 0..3
    const int r = (t >> 3) & 7;      // output row
    const int c = t & 7;             // output col
    float Dr[8], Dc[8];
    #pragma unroll
    for (int k = 0; k < 8; ++k) { Dr[k] = smem[DM + r * 8 + k]; Dc[k] = smem[DM + c * 8 + k]; }
    const int qi = r * 8 + c;
    const float qadd = (float)(0.5 / 255.0);
    // mul/add separately rounded (no FMA contraction) to match numpy
    const float den0 = __fadd_rn(__fmul_rn(quant[qi],        2.5f), qadd);
    const float den1 = __fadd_rn(__fmul_rn(quant[64 + qi],   2.5f), qadd);
    const float den2 = __fadd_rn(__fmul_rn(quant[128 + qi],  2.5f), qadd);

    #pragma unroll
    for (int it = 0; it < 6; ++it) {
        const int sb = it * 4 + g;       // sub-block 0..23, uniform per wave
        int xoff, ldx; size_t oidx; float den;
        if (sb < 16) {                   // Y blocks: 4x4 grid of 8x8 within the 32x32 tile
            const int sr = sb >> 2, sc = sb & 3;
            xoff = YT + sr * 8 * 36 + sc * 8; ldx = 36;
            const int bh = th * 4 + sr, bw = tw * 4 + sc;     // block coords in 64x64
            oidx = (((size_t)(b * 64 + bh)) * 64 + bw) * 64 + (r * 8 + c);
            den = den0;
        } else if (sb < 20) {            // Cb blocks: 2x2 grid of 8x8 within pooled 16x16
            const int s = sb - 16, sr = s >> 1, sc = s & 1;
            xoff = CB8 + sr * 8 * 18 + sc * 8; ldx = 18;
            const int bh = th * 2 + sr, bw = tw * 2 + sc;     // block coords in 32x32
            oidx = (size_t)4194304 + (((size_t)(b * 32 + bh)) * 32 + bw) * 64 + (r * 8 + c);
            den = den1;
        } else {                         // Cr blocks
            const int s = sb - 20, sr = s >> 1, sc = s & 1;
            xoff = CR8 + sr * 8 * 18 + sc * 8; ldx = 18;
            const int bh = th * 2 + sr, bw = tw * 2 + sc;
            oidx = (size_t)5242880 + (((size_t)(b * 32 + bh)) * 32 + bw) * 64 + (r * 8 + c);
            den = den2;
        }
        // stage 1: tmp[r][c] = sum_j D[r][j] * X[j][c]   (broadcast LDS reads)
        float s1 = 0.0f;
        #pragma unroll
        for (int j = 0; j < 8; ++j) s1 += Dr[j] * smem[xoff + j * ldx + c];
        __syncthreads();
        smem[TMP + g * 72 + r * 9 + c] = s1;
        __syncthreads();
        // stage 2: out[r][c] = sum_k tmp[r][k] * D[c][k]
        float s2 = 0.0f;
        #pragma unroll
        for (int k = 0; k < 8; ++k) s2 += smem[TMP + g * 72 + r * 9 + k] * Dc[k];
        out[oidx] = rintf(s2 / den);     // rintf = round half to even, matches jnp/np.round
    }
}

extern "C" void kernel_launch(void* const* d_in, const int* in_sizes, int n_in,
                              void* d_out, int out_size, void* d_ws, size_t ws_size,
                              hipStream_t stream) {
    const float* rgb   = (const float*)d_in[0];
    const float* quant = (const float*)d_in[1];
    float* out = (float*)d_out;
    dim3 grid(4096), block(256);
    hipLaunchKernelGGL(jpeg_kernel, grid, block, 0, stream, rgb, quant, out);
}